// Round 1
// 214.900 us; speedup vs baseline: 1.0892x; 1.0892x over previous
//
#include <hip/hip_runtime.h>
#include <cstdint>

#define Bb 4
#define Lseq 4096
#define Hh 1024
#define Nst 64
constexpr float LN_EPS = 1e-5f;

typedef _Float16 f16x8 __attribute__((ext_vector_type(8)));
typedef _Float16 f16x4 __attribute__((ext_vector_type(4)));
typedef float f32x4v __attribute__((ext_vector_type(4)));

// ---------------------------------------------------------------------------
// K0+K1 fused: precompute (blocks 0..1023) overlaps transpose (blocks 1024+).
// Precompute is transcendental/VALU-bound, transpose is HBM-bound -> free
// overlap instead of serial launches.
//
// Precompute: per h (5*4096 f16): [U_re | U_im | M1 (Tril K) | P_re | P_im_neg]
// Transpose: x [B,L,H] -> xt [B,H,L]; 64x64 tiles, float4 both ways,
//            LDS stride 65 (odd) -> 2-way aliasing max (free).
// ---------------------------------------------------------------------------
__global__ __launch_bounds__(256) void k_pre_trans(
    const float* __restrict__ x, float* __restrict__ xt,
    const float* __restrict__ logA, const float* __restrict__ Aim,
    const float* __restrict__ Cre, const float* __restrict__ Cim,
    const float* __restrict__ logdt, _Float16* __restrict__ mats,
    float* __restrict__ wwR, float* __restrict__ wwI) {
    __shared__ float tile[64 * 65];               // transpose path (16.6KB)
    __shared__ float sdAr[64], sdAi[64], scR[64], scI[64], sK[64];
    const int tid = threadIdx.x;

    if (blockIdx.x < Hh) {
        // ---------------- precompute path ----------------
        const int h = blockIdx.x;
        _Float16* g = mats + (size_t)h * 20480;

        if (tid < 64) {
            const int n = tid, idx = h * 64 + n;
            const float ar = -__expf(logA[idx]), ai = Aim[idx];
            const float dt = __expf(logdt[h]);
            const float dAr = dt * ar, dAi = dt * ai;
            const float em = __expf(dAr);
            const float wr = em * __cosf(dAi), wi = em * __sinf(dAi);
            const float Er = wr - 1.0f, Ei = wi;
            const float cr = Cre[idx], ci = Cim[idx];
            const float nr = cr * Er - ci * Ei, ni = cr * Ei + ci * Er;
            const float invd = 1.0f / (ar * ar + ai * ai);
            const float CtR = (nr * ar + ni * ai) * invd;
            const float CtI = (ni * ar - nr * ai) * invd;
            sdAr[n] = dAr; sdAi[n] = dAi;
            scR[n] = 2.0f * CtR; scI[n] = 2.0f * CtI;
            const float e64 = __expf(dAr * 64.0f), a64 = dAi * 64.0f;
            wwR[idx] = e64 * __cosf(a64);
            wwI[idx] = e64 * __sinf(a64);
        }
        __syncthreads();

        for (int e = tid; e < 4096; e += 256) {
            const int row = e >> 6, colj = e & 63;
            {
                const float p = (float)(63 - colj);
                const float ee = __expf(sdAr[row] * p), ang = sdAi[row] * p;
                g[e]        = (_Float16)(ee * __cosf(ang));
                g[4096 + e] = (_Float16)(ee * __sinf(ang));
            }
            {
                const int n = colj;
                const float q = (float)(row + 1);
                const float ee = __expf(sdAr[n] * q), ang = sdAi[n] * q;
                const float wRq = ee * __cosf(ang), wIq = ee * __sinf(ang);
                g[12288 + e] = (_Float16)(scR[n] * wRq - scI[n] * wIq);
                g[16384 + e] = (_Float16)(-(scR[n] * wIq + scI[n] * wRq));
            }
        }
        if (tid < 64) {
            const float tau = (float)tid;
            float sum = 0.0f;
            for (int n = 0; n < 64; ++n) {
                const float ee = __expf(sdAr[n] * tau), ang = sdAi[n] * tau;
                sum += ee * (scR[n] * __cosf(ang) - scI[n] * __sinf(ang));
            }
            sK[tid] = sum;
        }
        __syncthreads();
        for (int e = tid; e < 4096; e += 256) {
            const int t = e >> 6, j = e & 63;
            g[8192 + e] = (j <= t) ? (_Float16)sK[t - j] : (_Float16)0.0f;
        }
    } else {
        // ---------------- transpose path ----------------
        const int tb = blockIdx.x - Hh;
        const int h0 = (tb & 15) * 64;
        const int l0 = ((tb >> 4) & 63) * 64;
        const int b  = tb >> 10;
        const int c = tid & 15, r = tid >> 4;

        const float* src = x + ((size_t)(b * Lseq + l0 + r)) * Hh + h0 + 4 * c;
#pragma unroll
        for (int it = 0; it < 4; ++it) {
            const float4 v = *(const float4*)(src + (size_t)it * 16 * Hh);
            const int l = it * 16 + r;
            tile[(4 * c + 0) * 65 + l] = v.x;
            tile[(4 * c + 1) * 65 + l] = v.y;
            tile[(4 * c + 2) * 65 + l] = v.z;
            tile[(4 * c + 3) * 65 + l] = v.w;
        }
        __syncthreads();
        float* dst = xt + ((size_t)(b * Hh + h0 + r)) * Lseq + l0 + 4 * c;
#pragma unroll
        for (int it = 0; it < 4; ++it) {
            const float* trow = tile + (it * 16 + r) * 65 + 4 * c;
            float4 o;
            o.x = trow[0]; o.y = trow[1]; o.z = trow[2]; o.w = trow[3];
            *(float4*)(dst + (size_t)it * 16 * Lseq) = o;
        }
    }
}

// ---------------------------------------------------------------------------
// K2: chunked block-scan via MFMA. NOW 512 THREADS / 2 BATCHES PER BLOCK,
// grid (2, Hh). LDS trimmed to 80896B (mats stride 144 kept 16B-aligned for
// the 40 frag reads/wave; u/S at stride 136, read as 2x b64 for the 4 frag
// reads/wave) -> 2 BLOCKS/CU. Two independent blocks interleave their
// barrier/stage/scan phases, hiding the latency that a single resident
// block exposed (prev: Occ 37%, MfmaUtil 6.4%, nothing saturated).
// Bonus: u-writes at stride 136 hit all 32 banks 2-way (free) vs 4-way.
// ---------------------------------------------------------------------------
#define MR0 0        // U_re   f16 [64][72] stride 144B (16B aligned)
#define MI0 9216     // U_im
#define MM1 18432    // M1
#define MPR 27648    // P_re
#define MPI 36864    // P_im_neg
#define USB 46080    // 2 x { uR/S_R [64][68], uI/S_I [64][68] } stride 136B

#define MFRAG(base, row0, kk) \
    (*(const f16x8*)(sm + (base) + ((row0) + col) * 144 + ((kk) + qd * 8) * 2))

static __device__ __forceinline__ f16x8 ufrag(const unsigned char* sm, int off) {
    union { f16x8 v; f16x4 h[2]; } u;
    u.h[0] = *(const f16x4*)(sm + off);      // 8B aligned
    u.h[1] = *(const f16x4*)(sm + off + 8);
    return u.v;
}

__global__ __launch_bounds__(512, 4) void k_chunk(
    float* __restrict__ xt, const _Float16* __restrict__ mats,
    const float* __restrict__ wwR, const float* __restrict__ wwI,
    const float* __restrict__ Dp) {
    __shared__ __align__(16) unsigned char sm[80896];
    const int tid = threadIdx.x, lane = tid & 63, wv = tid >> 6;
    const int grp = wv >> 2;          // 0..1: which batch of this block's pair
    const int wb  = wv & 3;           // row-band wave 0..3
    const int h = blockIdx.y;
    const int b = blockIdx.x * 2 + grp;   // batch 0..3
    const _Float16* g = mats + (size_t)h * 20480;
    const int col = lane & 15, qd = lane >> 4;
    const int band = wb * 16;
    const int uRo = USB + grp * 17408;
    const int uIo = uRo + 8704;

    // ---- stage all 5 mats (40KB) into padded LDS ----
#pragma unroll
    for (int it = 0; it < 5; ++it) {
        const int chunk = it * 512 + tid;   // 16B units, 0..2559 exactly
        const int m = chunk >> 9;
        const int rem = chunk & 511;
        *(uint4*)(sm + m * 9216 + (rem >> 3) * 144 + (rem & 7) * 16) =
            *(const uint4*)(g + (size_t)chunk * 8);
    }

    const float Dp1 = 1.0f + Dp[h];
    float swR = 0.0f, swI = 0.0f;
    if (lane < 16) {
        swR = wwR[h * 64 + band + lane];
        swI = wwI[h * 64 + band + lane];
    }
    float* xr = xt + ((size_t)b * Hh + h) * Lseq;
    __syncthreads();  // mats staged

    // ---- phase 1: u = X @ U^T (complex); X from global -> registers ----
    f16x8 axk[2];
    f32x4v aR[4] = {}, aI[4] = {};
#pragma unroll
    for (int kh2 = 0; kh2 < 2; ++kh2) {
        const int kk = kh2 * 32;
        const float* xp = xr + (band + col) * 64 + kk + qd * 8;
        const float4 v0 = *(const float4*)(xp);
        const float4 v1 = *(const float4*)(xp + 4);
        f16x8 a;
        a[0] = (_Float16)v0.x; a[1] = (_Float16)v0.y;
        a[2] = (_Float16)v0.z; a[3] = (_Float16)v0.w;
        a[4] = (_Float16)v1.x; a[5] = (_Float16)v1.y;
        a[6] = (_Float16)v1.z; a[7] = (_Float16)v1.w;
        axk[kh2] = a;
#pragma unroll
        for (int nt = 0; nt < 4; ++nt) {
            aR[nt] = __builtin_amdgcn_mfma_f32_16x16x32_f16(
                a, MFRAG(MR0, nt * 16, kk), aR[nt], 0, 0, 0);
            aI[nt] = __builtin_amdgcn_mfma_f32_16x16x32_f16(
                a, MFRAG(MI0, nt * 16, kk), aI[nt], 0, 0, 0);
        }
    }
#pragma unroll
    for (int nt = 0; nt < 4; ++nt)
#pragma unroll
        for (int rg = 0; rg < 4; ++rg) {
            const int cc = band + qd * 4 + rg, n = nt * 16 + col;
            *(_Float16*)(sm + uRo + cc * 136 + n * 2) = (_Float16)aR[nt][rg];
            *(_Float16*)(sm + uIo + cc * 136 + n * 2) = (_Float16)aI[nt][rg];
        }
    __syncthreads();  // u visible

    // ---- phase 2: chunk-level scan, in-place u->S; wave owns 16 n ----
    if (lane < 16) {
        const int n = band + lane;
        float sR = 0.0f, sI = 0.0f;
        for (int c = 0; c < 64; ++c) {
            _Float16* pR = (_Float16*)(sm + uRo + c * 136 + n * 2);
            _Float16* pI = (_Float16*)(sm + uIo + c * 136 + n * 2);
            const float uRv = (float)*pR;
            const float uIv = (float)*pI;
            *pR = (_Float16)sR;
            *pI = (_Float16)sI;
            const float nR = fmaf(swR, sR, fmaf(-swI, sI, uRv));
            sI = fmaf(swR, sI, fmaf(swI, sR, uIv));
            sR = nR;
        }
    }
    __syncthreads();  // S visible

    // ---- phase 3: y = X@M1^T + SR@PR^T + SI@PIneg^T ----
    f32x4v acc[4] = {};
#pragma unroll
    for (int kh2 = 0; kh2 < 2; ++kh2) {
        const int kk = kh2 * 32;
#pragma unroll
        for (int tt = 0; tt < 4; ++tt)
            acc[tt] = __builtin_amdgcn_mfma_f32_16x16x32_f16(
                axk[kh2], MFRAG(MM1, tt * 16, kk), acc[tt], 0, 0, 0);
    }
#pragma unroll
    for (int kh2 = 0; kh2 < 2; ++kh2) {
        const int kk = kh2 * 32;
        const f16x8 as = ufrag(sm, uRo + (band + col) * 136 + (kk + qd * 8) * 2);
#pragma unroll
        for (int tt = 0; tt < 4; ++tt)
            acc[tt] = __builtin_amdgcn_mfma_f32_16x16x32_f16(
                as, MFRAG(MPR, tt * 16, kk), acc[tt], 0, 0, 0);
    }
#pragma unroll
    for (int kh2 = 0; kh2 < 2; ++kh2) {
        const int kk = kh2 * 32;
        const f16x8 az = ufrag(sm, uIo + (band + col) * 136 + (kk + qd * 8) * 2);
#pragma unroll
        for (int tt = 0; tt < 4; ++tt)
            acc[tt] = __builtin_amdgcn_mfma_f32_16x16x32_f16(
                az, MFRAG(MPI, tt * 16, kk), acc[tt], 0, 0, 0);
    }

    // ---- epilogue: r = x*(1+D) + y, straight from accumulators ----
#pragma unroll
    for (int tt = 0; tt < 4; ++tt)
#pragma unroll
        for (int rg = 0; rg < 4; ++rg) {
            const int l = (band + qd * 4 + rg) * 64 + tt * 16 + col;
            xr[l] = fmaf(xr[l], Dp1, acc[tt][rg]);
        }
}

// ---------------------------------------------------------------------------
// K3: single-pass LayerNorm + transpose back: rt [B,H,L] -> out [B,L,H].
// tile stride 1033 (odd): LDS write aliasing 4-way -> ~2-way.
// ---------------------------------------------------------------------------
__global__ __launch_bounds__(512, 2) void k_ln(const float* __restrict__ rt,
                                               float* __restrict__ out,
                                               const float* __restrict__ lnw,
                                               const float* __restrict__ lnb) {
    __shared__ float tile[16 * 1033];
    __shared__ float ps[32][17], pq[32][17];
    __shared__ float mm[16], rs[16];
    const int b  = blockIdx.y;
    const int l0 = blockIdx.x * 16;
    const int tid = threadIdx.x;
    const int ll = tid & 15;
    const int hh = tid >> 4;  // 0..31

    const float* base = rt + (size_t)b * Hh * Lseq + l0;

    float psum = 0.0f, psq = 0.0f;
#pragma unroll 8
    for (int hc = 0; hc < Hh; hc += 32) {
        const float v = base[(size_t)(hc + hh) * Lseq + ll];
        tile[ll * 1033 + hc + hh] = v;
        psum += v;
        psq = fmaf(v, v, psq);
    }
    ps[hh][ll] = psum;
    pq[hh][ll] = psq;
    __syncthreads();
    if (tid < 16) {
        float s = 0.f, q = 0.f;
#pragma unroll
        for (int k = 0; k < 32; ++k) {
            s += ps[k][tid];
            q += pq[k][tid];
        }
        const float mu  = s * (1.0f / Hh);
        const float var = fmaf(-mu, mu, q * (1.0f / Hh));
        mm[tid] = mu;
        rs[tid] = rsqrtf(var + LN_EPS);
    }
    __syncthreads();

    const float w0 = lnw[tid],       b0 = lnb[tid];
    const float w1 = lnw[512 + tid], b1 = lnb[512 + tid];
    float* obase = out + ((size_t)b * Lseq + l0) * Hh;
#pragma unroll 4
    for (int l = 0; l < 16; ++l) {
        const float mu = mm[l], rsg = rs[l];
        const float v0 = tile[l * 1033 + tid];
        const float v1 = tile[l * 1033 + 512 + tid];
        obase[(size_t)l * Hh + tid]       = fmaf((v0 - mu) * rsg, w0, b0);
        obase[(size_t)l * Hh + 512 + tid] = fmaf((v1 - mu) * rsg, w1, b1);
    }
}

// ---------------------------------------------------------------------------
extern "C" void kernel_launch(void* const* d_in, const int* in_sizes, int n_in,
                              void* d_out, int out_size, void* d_ws, size_t ws_size,
                              hipStream_t stream) {
    const float* x     = (const float*)d_in[0];
    const float* logA  = (const float*)d_in[1];
    const float* Aim   = (const float*)d_in[2];
    const float* Cre   = (const float*)d_in[3];
    const float* Cim   = (const float*)d_in[4];
    const float* logdt = (const float*)d_in[5];
    const float* Dp    = (const float*)d_in[6];
    const float* lnw   = (const float*)d_in[7];
    const float* lnb   = (const float*)d_in[8];
    float* out = (float*)d_out;
    float* ws  = (float*)d_ws;  // 64 MiB: xt/r [B,H,L]

    _Float16* mats = (_Float16*)d_out;                          // 40 MiB
    float* wwR = (float*)((char*)d_out + 41943040);             // 256 KiB
    float* wwI = (float*)((char*)d_out + 42205184);             // 256 KiB

    // precompute blocks (0..1023) overlap transpose blocks (1024..5119)
    k_pre_trans<<<dim3(Hh + (Hh / 64) * (Lseq / 64) * Bb), 256, 0, stream>>>(
        x, ws, logA, Aim, Cre, Cim, logdt, mats, wwR, wwI);
    k_chunk<<<dim3(2, Hh), 512, 0, stream>>>(ws, mats, wwR, wwI, Dp);
    k_ln<<<dim3(Lseq / 16, Bb), 512, 0, stream>>>(ws, out, lnw, lnb);
}

// Round 2
// 212.635 us; speedup vs baseline: 1.1008x; 1.0107x over previous
//
#include <hip/hip_runtime.h>
#include <cstdint>

#define Bb 4
#define Lseq 4096
#define Hh 1024
#define Nst 64
constexpr float LN_EPS = 1e-5f;

typedef _Float16 f16x8 __attribute__((ext_vector_type(8)));
typedef _Float16 f16x4 __attribute__((ext_vector_type(4)));
typedef float f32x4v __attribute__((ext_vector_type(4)));

typedef const __attribute__((address_space(1))) void* gas_vp;
typedef __attribute__((address_space(3))) void* las_vp;

// XOR-swizzle within a 64x64 f16 matrix: elem e=(row*64+col) stored at
// e ^ ((row&7)<<3)  (byte ^= ((row&7)<<4)). Written pre-swizzled by k_pre so
// identity global->LDS staging (global_load_lds) lands the swizzled layout;
// fragment reads in k_chunk apply the same XOR -> conflict-free ds_read_b128.
__device__ __forceinline__ int swz(int e) { return e ^ (((e >> 6) & 7) << 3); }

// ---------------------------------------------------------------------------
// K0+K1 fused: precompute (blocks 0..1023) overlaps transpose (blocks 1024+).
// ---------------------------------------------------------------------------
__global__ __launch_bounds__(256) void k_pre_trans(
    const float* __restrict__ x, float* __restrict__ xt,
    const float* __restrict__ logA, const float* __restrict__ Aim,
    const float* __restrict__ Cre, const float* __restrict__ Cim,
    const float* __restrict__ logdt, _Float16* __restrict__ mats,
    float* __restrict__ wwR, float* __restrict__ wwI) {
    __shared__ float tile[64 * 65];               // transpose path (16.6KB)
    __shared__ float sdAr[64], sdAi[64], scR[64], scI[64], sK[64];
    const int tid = threadIdx.x;

    if (blockIdx.x < Hh) {
        // ---------------- precompute path ----------------
        const int h = blockIdx.x;
        _Float16* g = mats + (size_t)h * 20480;

        if (tid < 64) {
            const int n = tid, idx = h * 64 + n;
            const float ar = -__expf(logA[idx]), ai = Aim[idx];
            const float dt = __expf(logdt[h]);
            const float dAr = dt * ar, dAi = dt * ai;
            const float em = __expf(dAr);
            const float wr = em * __cosf(dAi), wi = em * __sinf(dAi);
            const float Er = wr - 1.0f, Ei = wi;
            const float cr = Cre[idx], ci = Cim[idx];
            const float nr = cr * Er - ci * Ei, ni = cr * Ei + ci * Er;
            const float invd = 1.0f / (ar * ar + ai * ai);
            const float CtR = (nr * ar + ni * ai) * invd;
            const float CtI = (ni * ar - nr * ai) * invd;
            sdAr[n] = dAr; sdAi[n] = dAi;
            scR[n] = 2.0f * CtR; scI[n] = 2.0f * CtI;
            const float e64 = __expf(dAr * 64.0f), a64 = dAi * 64.0f;
            wwR[idx] = e64 * __cosf(a64);
            wwI[idx] = e64 * __sinf(a64);
        }
        __syncthreads();

        for (int e = tid; e < 4096; e += 256) {
            const int row = e >> 6, colj = e & 63;
            const int es = swz(e);
            {
                const float p = (float)(63 - colj);
                const float ee = __expf(sdAr[row] * p), ang = sdAi[row] * p;
                g[es]        = (_Float16)(ee * __cosf(ang));
                g[4096 + es] = (_Float16)(ee * __sinf(ang));
            }
            {
                const int n = colj;
                const float q = (float)(row + 1);
                const float ee = __expf(sdAr[n] * q), ang = sdAi[n] * q;
                const float wRq = ee * __cosf(ang), wIq = ee * __sinf(ang);
                g[12288 + es] = (_Float16)(scR[n] * wRq - scI[n] * wIq);
                g[16384 + es] = (_Float16)(-(scR[n] * wIq + scI[n] * wRq));
            }
        }
        if (tid < 64) {
            const float tau = (float)tid;
            float sum = 0.0f;
            for (int n = 0; n < 64; ++n) {
                const float ee = __expf(sdAr[n] * tau), ang = sdAi[n] * tau;
                sum += ee * (scR[n] * __cosf(ang) - scI[n] * __sinf(ang));
            }
            sK[tid] = sum;
        }
        __syncthreads();
        for (int e = tid; e < 4096; e += 256) {
            const int t = e >> 6, j = e & 63;
            g[8192 + swz(e)] = (j <= t) ? (_Float16)sK[t - j] : (_Float16)0.0f;
        }
    } else {
        // ---------------- transpose path ----------------
        const int tb = blockIdx.x - Hh;
        const int h0 = (tb & 15) * 64;
        const int l0 = ((tb >> 4) & 63) * 64;
        const int b  = tb >> 10;
        const int c = tid & 15, r = tid >> 4;

        const float* src = x + ((size_t)(b * Lseq + l0 + r)) * Hh + h0 + 4 * c;
#pragma unroll
        for (int it = 0; it < 4; ++it) {
            const float4 v = *(const float4*)(src + (size_t)it * 16 * Hh);
            const int l = it * 16 + r;
            tile[(4 * c + 0) * 65 + l] = v.x;
            tile[(4 * c + 1) * 65 + l] = v.y;
            tile[(4 * c + 2) * 65 + l] = v.z;
            tile[(4 * c + 3) * 65 + l] = v.w;
        }
        __syncthreads();
        float* dst = xt + ((size_t)(b * Hh + h0 + r)) * Lseq + l0 + 4 * c;
#pragma unroll
        for (int it = 0; it < 4; ++it) {
            const float* trow = tile + (it * 16 + r) * 65 + 4 * c;
            float4 o;
            o.x = trow[0]; o.y = trow[1]; o.z = trow[2]; o.w = trow[3];
            *(float4*)(dst + (size_t)it * 16 * Lseq) = o;
        }
    }
}

// ---------------------------------------------------------------------------
// K2: chunked block-scan via MFMA. 512 threads / 2 batches per block,
// grid (2, Hh), 2 blocks/CU. This round:
//  - mats staged via ASYNC global_load_lds (identity copy of pre-swizzled
//    data, unpadded stride 128B + XOR swizzle) -> no VGPR round-trip, stage
//    latency overlaps the phase-1 x loads; LDS 80896 -> 75776.
//  - epilogue x reads hoisted above phase-3 MFMA cluster (write-only epilogue)
//  - s_setprio(1) around MFMA clusters (2 independent resident blocks =
//    wave role diversity, attn-like regime where setprio measured +4-7%)
// ---------------------------------------------------------------------------
#define MR0 0        // U_re   f16 [64][64] stride 128B, XOR-swizzled
#define MI0 8192     // U_im
#define MM1 16384    // M1
#define MPR 24576    // P_re
#define MPI 32768    // P_im_neg
#define USB 40960    // 2 x { uR/S_R [64][68], uI/S_I [64][68] } stride 136B

// row0 is a multiple of 16 at every use, so (row0+col)&7 == col&7
#define MFRAG(base, row0, kk) \
    (*(const f16x8*)(sm + (((base) + ((row0) + col) * 128 + ((kk) + qd * 8) * 2) ^ ((col & 7) << 4))))

static __device__ __forceinline__ f16x8 ufrag(const unsigned char* sm, int off) {
    union { f16x8 v; f16x4 h[2]; } u;
    u.h[0] = *(const f16x4*)(sm + off);      // 8B aligned
    u.h[1] = *(const f16x4*)(sm + off + 8);
    return u.v;
}

__global__ __launch_bounds__(512, 4) void k_chunk(
    float* __restrict__ xt, const _Float16* __restrict__ mats,
    const float* __restrict__ wwR, const float* __restrict__ wwI,
    const float* __restrict__ Dp) {
    __shared__ __align__(16) unsigned char sm[75776];
    const int tid = threadIdx.x, lane = tid & 63, wv = tid >> 6;
    const int grp = wv >> 2;          // 0..1: which batch of this block's pair
    const int wb  = wv & 3;           // row-band wave 0..3
    const int h = blockIdx.y;
    const int b = blockIdx.x * 2 + grp;   // batch 0..3
    const _Float16* g = mats + (size_t)h * 20480;
    const int col = lane & 15, qd = lane >> 4;
    const int band = wb * 16;
    const int uRo = USB + grp * 17408;
    const int uIo = uRo + 8704;

    // ---- async stage: 40KB mats, identity global->LDS (pre-swizzled) ----
#pragma unroll
    for (int it = 0; it < 5; ++it) {
        const int blk = it * 8 + wv;          // 1KB block, 0..39
        __builtin_amdgcn_global_load_lds(
            (gas_vp)((const uint4*)g + blk * 64 + lane),
            (las_vp)(sm + blk * 1024), 16, 0, 0);
    }

    const float Dp1 = 1.0f + Dp[h];
    float swR = 0.0f, swI = 0.0f;
    if (lane < 16) {
        swR = wwR[h * 64 + band + lane];
        swI = wwI[h * 64 + band + lane];
    }
    float* xr = xt + ((size_t)b * Hh + h) * Lseq;

    // ---- phase-1 x loads issued NOW: latency overlaps the mats stage ----
    float4 xv0[2], xv1[2];
#pragma unroll
    for (int kh2 = 0; kh2 < 2; ++kh2) {
        const float* xp = xr + (band + col) * 64 + kh2 * 32 + qd * 8;
        xv0[kh2] = *(const float4*)(xp);
        xv1[kh2] = *(const float4*)(xp + 4);
    }
    f16x8 axk[2];
#pragma unroll
    for (int kh2 = 0; kh2 < 2; ++kh2) {
        f16x8 a;
        a[0] = (_Float16)xv0[kh2].x; a[1] = (_Float16)xv0[kh2].y;
        a[2] = (_Float16)xv0[kh2].z; a[3] = (_Float16)xv0[kh2].w;
        a[4] = (_Float16)xv1[kh2].x; a[5] = (_Float16)xv1[kh2].y;
        a[6] = (_Float16)xv1[kh2].z; a[7] = (_Float16)xv1[kh2].w;
        axk[kh2] = a;
    }
    __syncthreads();  // mats staged (vmcnt drain also covers x loads)

    // ---- phase 1: u = X @ U^T (complex) ----
    f32x4v aR[4] = {}, aI[4] = {};
    __builtin_amdgcn_s_setprio(1);
#pragma unroll
    for (int kh2 = 0; kh2 < 2; ++kh2) {
        const int kk = kh2 * 32;
#pragma unroll
        for (int nt = 0; nt < 4; ++nt) {
            aR[nt] = __builtin_amdgcn_mfma_f32_16x16x32_f16(
                axk[kh2], MFRAG(MR0, nt * 16, kk), aR[nt], 0, 0, 0);
            aI[nt] = __builtin_amdgcn_mfma_f32_16x16x32_f16(
                axk[kh2], MFRAG(MI0, nt * 16, kk), aI[nt], 0, 0, 0);
        }
    }
    __builtin_amdgcn_s_setprio(0);
#pragma unroll
    for (int nt = 0; nt < 4; ++nt)
#pragma unroll
        for (int rg = 0; rg < 4; ++rg) {
            const int cc = band + qd * 4 + rg, n = nt * 16 + col;
            *(_Float16*)(sm + uRo + cc * 136 + n * 2) = (_Float16)aR[nt][rg];
            *(_Float16*)(sm + uIo + cc * 136 + n * 2) = (_Float16)aI[nt][rg];
        }
    __syncthreads();  // u visible

    // ---- phase 2: chunk-level scan, in-place u->S; wave owns 16 n ----
    if (lane < 16) {
        const int n = band + lane;
        float sR = 0.0f, sI = 0.0f;
        for (int c = 0; c < 64; ++c) {
            _Float16* pR = (_Float16*)(sm + uRo + c * 136 + n * 2);
            _Float16* pI = (_Float16*)(sm + uIo + c * 136 + n * 2);
            const float uRv = (float)*pR;
            const float uIv = (float)*pI;
            *pR = (_Float16)sR;
            *pI = (_Float16)sI;
            const float nR = fmaf(swR, sR, fmaf(-swI, sI, uRv));
            sI = fmaf(swR, sI, fmaf(swI, sR, uIv));
            sR = nR;
        }
    }
    __syncthreads();  // S visible

    // ---- hoist epilogue x reads: latency hides under phase-3 MFMAs ----
    float xold[4][4];
#pragma unroll
    for (int tt = 0; tt < 4; ++tt)
#pragma unroll
        for (int rg = 0; rg < 4; ++rg)
            xold[tt][rg] = xr[(band + qd * 4 + rg) * 64 + tt * 16 + col];

    // ---- phase 3: y = X@M1^T + SR@PR^T + SI@PIneg^T ----
    f32x4v acc[4] = {};
    __builtin_amdgcn_s_setprio(1);
#pragma unroll
    for (int kh2 = 0; kh2 < 2; ++kh2) {
        const int kk = kh2 * 32;
#pragma unroll
        for (int tt = 0; tt < 4; ++tt)
            acc[tt] = __builtin_amdgcn_mfma_f32_16x16x32_f16(
                axk[kh2], MFRAG(MM1, tt * 16, kk), acc[tt], 0, 0, 0);
    }
#pragma unroll
    for (int kh2 = 0; kh2 < 2; ++kh2) {
        const int kk = kh2 * 32;
        const f16x8 as = ufrag(sm, uRo + (band + col) * 136 + (kk + qd * 8) * 2);
#pragma unroll
        for (int tt = 0; tt < 4; ++tt)
            acc[tt] = __builtin_amdgcn_mfma_f32_16x16x32_f16(
                as, MFRAG(MPR, tt * 16, kk), acc[tt], 0, 0, 0);
    }
#pragma unroll
    for (int kh2 = 0; kh2 < 2; ++kh2) {
        const int kk = kh2 * 32;
        const f16x8 az = ufrag(sm, uIo + (band + col) * 136 + (kk + qd * 8) * 2);
#pragma unroll
        for (int tt = 0; tt < 4; ++tt)
            acc[tt] = __builtin_amdgcn_mfma_f32_16x16x32_f16(
                az, MFRAG(MPI, tt * 16, kk), acc[tt], 0, 0, 0);
    }
    __builtin_amdgcn_s_setprio(0);

    // ---- epilogue: r = x*(1+D) + y, write-only ----
#pragma unroll
    for (int tt = 0; tt < 4; ++tt)
#pragma unroll
        for (int rg = 0; rg < 4; ++rg) {
            const int l = (band + qd * 4 + rg) * 64 + tt * 16 + col;
            xr[l] = fmaf(xold[tt][rg], Dp1, acc[tt][rg]);
        }
}

// ---------------------------------------------------------------------------
// K3: single-pass LayerNorm + transpose back: rt [B,H,L] -> out [B,L,H].
// v2: float4 reads along L (4x fewer VMEM instrs), float4 writes along H,
// in-wave shuffle butterfly for the partial reduction. Tile stride 1028
// words (16B-aligned for b128 reads; write aliasing 2-way = free).
// ---------------------------------------------------------------------------
__global__ __launch_bounds__(512, 2) void k_ln(const float* __restrict__ rt,
                                               float* __restrict__ out,
                                               const float* __restrict__ lnw,
                                               const float* __restrict__ lnb) {
    __shared__ float tile[16 * 1028];
    __shared__ float ps[8 * 16], pq[8 * 16];
    __shared__ float mm[16], rs[16];
    const int b  = blockIdx.y;
    const int l0 = blockIdx.x * 16;
    const int tid = threadIdx.x;
    const int lq = tid & 3;        // l-quad: handles l = lq*4 .. lq*4+3
    const int hr = tid >> 2;       // 0..127 base row
    const int lane = tid & 63, wvv = tid >> 6;

    const float* base = rt + (size_t)b * Hh * Lseq + l0 + lq * 4;

    float s0 = 0, s1 = 0, s2 = 0, s3 = 0, q0 = 0, q1 = 0, q2 = 0, q3 = 0;
#pragma unroll
    for (int p = 0; p < 8; ++p) {
        const int row = hr + p * 128;
        const float4 v = *(const float4*)(base + (size_t)row * Lseq);
        float* tw = tile + lq * 4 * 1028 + row;
        tw[0] = v.x; tw[1028] = v.y; tw[2056] = v.z; tw[3084] = v.w;
        s0 += v.x; q0 = fmaf(v.x, v.x, q0);
        s1 += v.y; q1 = fmaf(v.y, v.y, q1);
        s2 += v.z; q2 = fmaf(v.z, v.z, q2);
        s3 += v.w; q3 = fmaf(v.w, v.w, q3);
    }
    // butterfly over hr bits within the wave (lane bits 2..5)
#pragma unroll
    for (int d = 4; d <= 32; d <<= 1) {
        s0 += __shfl_xor(s0, d); q0 += __shfl_xor(q0, d);
        s1 += __shfl_xor(s1, d); q1 += __shfl_xor(q1, d);
        s2 += __shfl_xor(s2, d); q2 += __shfl_xor(q2, d);
        s3 += __shfl_xor(s3, d); q3 += __shfl_xor(q3, d);
    }
    if ((lane >> 2) == 0) {   // lanes 0..3, one per lq
        float* pp = ps + wvv * 16 + lq * 4;
        float* qq = pq + wvv * 16 + lq * 4;
        pp[0] = s0; pp[1] = s1; pp[2] = s2; pp[3] = s3;
        qq[0] = q0; qq[1] = q1; qq[2] = q2; qq[3] = q3;
    }
    __syncthreads();
    if (tid < 16) {
        float s = 0.f, q = 0.f;
#pragma unroll
        for (int w = 0; w < 8; ++w) { s += ps[w * 16 + tid]; q += pq[w * 16 + tid]; }
        const float mu  = s * (1.0f / Hh);
        const float var = fmaf(-mu, mu, q * (1.0f / Hh));
        mm[tid] = mu;
        rs[tid] = rsqrtf(var + LN_EPS);
    }
    __syncthreads();

    const int hq = tid & 255, lsel = tid >> 8;
    const float4 wv4 = *(const float4*)(lnw + hq * 4);
    const float4 bv4 = *(const float4*)(lnb + hq * 4);
    float* obase = out + ((size_t)b * Lseq + l0) * Hh + hq * 4;
#pragma unroll
    for (int pl = 0; pl < 8; ++pl) {
        const int l = pl * 2 + lsel;
        const float mu = mm[l], rsg = rs[l];
        const float4 v = *(const float4*)(tile + l * 1028 + hq * 4);
        float4 o;
        o.x = fmaf((v.x - mu) * rsg, wv4.x, bv4.x);
        o.y = fmaf((v.y - mu) * rsg, wv4.y, bv4.y);
        o.z = fmaf((v.z - mu) * rsg, wv4.z, bv4.z);
        o.w = fmaf((v.w - mu) * rsg, wv4.w, bv4.w);
        *(float4*)(obase + (size_t)l * Hh) = o;
    }
}

// ---------------------------------------------------------------------------
extern "C" void kernel_launch(void* const* d_in, const int* in_sizes, int n_in,
                              void* d_out, int out_size, void* d_ws, size_t ws_size,
                              hipStream_t stream) {
    const float* x     = (const float*)d_in[0];
    const float* logA  = (const float*)d_in[1];
    const float* Aim   = (const float*)d_in[2];
    const float* Cre   = (const float*)d_in[3];
    const float* Cim   = (const float*)d_in[4];
    const float* logdt = (const float*)d_in[5];
    const float* Dp    = (const float*)d_in[6];
    const float* lnw   = (const float*)d_in[7];
    const float* lnb   = (const float*)d_in[8];
    float* out = (float*)d_out;
    float* ws  = (float*)d_ws;  // 64 MiB: xt/r [B,H,L]

    _Float16* mats = (_Float16*)d_out;                          // 40 MiB
    float* wwR = (float*)((char*)d_out + 41943040);             // 256 KiB
    float* wwI = (float*)((char*)d_out + 42205184);             // 256 KiB

    // precompute blocks (0..1023) overlap transpose blocks (1024..5119)
    k_pre_trans<<<dim3(Hh + (Hh / 64) * (Lseq / 64) * Bb), 256, 0, stream>>>(
        x, ws, logA, Aim, Cre, Cim, logdt, mats, wwR, wwI);
    k_chunk<<<dim3(2, Hh), 512, 0, stream>>>(ws, mats, wwR, wwI, Dp);
    k_ln<<<dim3(Lseq / 16, Bb), 512, 0, stream>>>(ws, out, lnw, lnb);
}